// Round 7
// baseline (12.397 us; speedup 1.0000x reference)
//
#include <hip/hip_runtime.h>

// PairwiseRankingLoss: B=128 rows, L=1024.
// loss = sum_{b, pos i, neg j} relu(1 - s[b,i] + s[b,j]) / max(num_pairs, 1)
//
// K1: grid = B*SPLIT (SPLIT=4) blocks. Each block ballot-compacts its row into
//     dense pos[] / neg[] LDS arrays (labels are {0,1} so neg-mask = ~pos-mask,
//     nn = L - np), then computes the hinge over (all pos) x (its quarter of
//     the compacted negs). Partial sums to distinct ws slots; the s==0 block
//     writes the exact pair count np*(L-np).
// K2: one 64-thread wave reduces the 512 partials and writes the loss.

#define PRL_B 128
#define PRL_L 1024
#define SPLIT 4
#define NBLK  (PRL_B * SPLIT)   // 512 blocks

// Hot loop specialized on K = pos values per thread (block-uniform runtime).
template<int K>
__device__ __forceinline__ float hotloop(const float4* __restrict__ d4,
                                         int c0, int c1, float4 pv) {
    float acc[K];
#pragma unroll
    for (int k = 0; k < K; ++k) acc[k] = 0.f;
#pragma unroll 2
    for (int c = c0; c < c1; ++c) {
        const float4 d = d4[c];   // wave-uniform LDS broadcast
#pragma unroll
        for (int k = 0; k < K; ++k) {
            const float pk = (k == 0) ? pv.x : (k == 1) ? pv.y : (k == 2) ? pv.z : pv.w;
            acc[k] += (fmaxf(d.x - pk, 0.f) + fmaxf(d.y - pk, 0.f))
                    + (fmaxf(d.z - pk, 0.f) + fmaxf(d.w - pk, 0.f));
        }
    }
    float r = 0.f;
#pragma unroll
    for (int k = 0; k < K; ++k) r += acc[k];
    return r;
}

__global__ __launch_bounds__(256) void prl_partial(
    const float* __restrict__ y_pred,
    const int*   __restrict__ y_true,
    float* __restrict__ bsum,    // [NBLK]
    int*   __restrict__ bpairs)  // [NBLK]
{
    __shared__ float4 s_pos4[PRL_L / 4];   // compacted pos scores (+3e38 pad)
    __shared__ float4 s_neg4[PRL_L / 4];   // compacted 1+neg scores (-3e38 pad)
    __shared__ int    s_cntP[4];
    __shared__ float  s_wsum[4];
    float* s_pos = (float*)s_pos4;
    float* s_neg = (float*)s_neg4;

    const int blk  = blockIdx.x;
    const int b    = blk >> 2;            // / SPLIT
    const int s    = blk & (SPLIT - 1);
    const int t    = threadIdx.x;
    const int lane = t & 63;
    const int w    = t >> 6;

    // Vectorized staging: one float4 + one int4 per thread covers the row.
    // Element e = 256*w + 4*lane + r.
    const float4 sc = ((const float4*)(y_pred + (size_t)b * PRL_L))[t];
    const int4   lv = ((const int4*)  (y_true + (size_t)b * PRL_L))[t];
    const float sv[4] = {sc.x, sc.y, sc.z, sc.w};
    const int   lb[4] = {lv.x, lv.y, lv.z, lv.w};

    // Pass 1: per-wave pos masks via ballot; labels in {0,1} => neg = ~pos.
    unsigned long long mP[4];
    int cP = 0;
#pragma unroll
    for (int r = 0; r < 4; ++r) {
        mP[r] = __ballot(lb[r] == 1);
        cP += (int)__popcll(mP[r]);
    }
    if (lane == 0) s_cntP[w] = cP;

    // Sentinel-init (pad regions survive; valid regions overwritten below).
    s_pos4[t] = make_float4( 3.0e38f,  3.0e38f,  3.0e38f,  3.0e38f);
    s_neg4[t] = make_float4(-3.0e38f, -3.0e38f, -3.0e38f, -3.0e38f);
    __syncthreads();

    // Wave offsets + row totals (np; nn = L - np).
    int offP = 0, np = 0;
#pragma unroll
    for (int ww = 0; ww < 4; ++ww) {
        const int p_ = s_cntP[ww];
        np += p_;
        if (ww < w) offP += p_;
    }
    const int nn   = PRL_L - np;
    const int offN = 256 * w - offP;

    // Pass 2: scatter compacted values (order irrelevant).
    const unsigned long long lt = (1ULL << lane) - 1ULL;
    int bP = offP, bN = offN;
#pragma unroll
    for (int r = 0; r < 4; ++r) {
        const unsigned long long mp = mP[r], mn = ~mp;
        if (lb[r] == 1) s_pos[bP + (int)__popcll(mp & lt)] = sv[r];
        else            s_neg[bN + (int)__popcll(mn & lt)] = 1.0f + sv[r];
        bP += (int)__popcll(mp);
        bN += 64 - (int)__popcll(mp);
    }
    __syncthreads();

    // This thread's pos values (sentinel-padded reads are safe).
    const float4 pv = make_float4(s_pos[t], s_pos[t + 256],
                                  s_pos[t + 512], s_pos[t + 768]);
    const int KP  = (np + 255) >> 8;              // 0..4, block-uniform
    const int NN4 = (nn + 3) >> 2;                // float4 groups of negs
    const int G   = (NN4 + SPLIT - 1) / SPLIT;    // groups per slice
    const int c0  = min(s * G, NN4);
    const int c1  = min(c0 + G, NN4);

    float local;
    switch (KP) {
        case 0:  local = 0.f; break;
        case 1:  local = hotloop<1>(s_neg4, c0, c1, pv); break;
        case 2:  local = hotloop<2>(s_neg4, c0, c1, pv); break;
        case 3:  local = hotloop<3>(s_neg4, c0, c1, pv); break;
        default: local = hotloop<4>(s_neg4, c0, c1, pv); break;
    }

    // Block reduction (sum only; pair count is uniform, no reduce needed).
#pragma unroll
    for (int off = 32; off >= 1; off >>= 1)
        local += __shfl_down(local, off, 64);
    if (lane == 0) s_wsum[w] = local;
    __syncthreads();

    if (t == 0) {
        bsum[blk]   = (s_wsum[0] + s_wsum[1]) + (s_wsum[2] + s_wsum[3]);
        bpairs[blk] = (s == 0) ? np * nn : 0;   // exact pair count, once/row
    }
}

// Single-wave finalize: 64 threads read all 512 partials (4 KB, L2-hot).
__global__ __launch_bounds__(64) void prl_finalize(
    const float* __restrict__ bsum,
    const int*   __restrict__ bpairs,
    float* __restrict__ out)
{
    const int t = threadIdx.x;
    const float4* s4 = (const float4*)bsum;
    const int4*   p4 = (const int4*)bpairs;

    float fs = 0.f; int ps = 0;
#pragma unroll
    for (int k = 0; k < 2; ++k) {           // 2 x 64 float4 = 512 partials
        const float4 a = s4[t + 64 * k];
        const int4  ia = p4[t + 64 * k];
        fs += (a.x + a.y) + (a.z + a.w);
        ps += (ia.x + ia.y) + (ia.z + ia.w);
    }
#pragma unroll
    for (int off = 32; off >= 1; off >>= 1) {
        fs += __shfl_down(fs, off, 64);
        ps += __shfl_down(ps, off, 64);
    }
    if (t == 0)
        out[0] = (ps > 0) ? (fs / fmaxf((float)ps, 1.0f)) : fs;
}

extern "C" void kernel_launch(void* const* d_in, const int* in_sizes, int n_in,
                              void* d_out, int out_size, void* d_ws, size_t ws_size,
                              hipStream_t stream) {
    const float* y_pred = (const float*)d_in[0];
    const int*   y_true = (const int*)d_in[1];
    float* out = (float*)d_out;

    // ws layout: float bsum[NBLK]; int bpairs[NBLK]
    float* bsum   = (float*)d_ws;
    int*   bpairs = (int*)((char*)d_ws + NBLK * sizeof(float));

    prl_partial<<<NBLK, 256, 0, stream>>>(y_pred, y_true, bsum, bpairs);
    prl_finalize<<<1, 64, 0, stream>>>(bsum, bpairs, out);
}

// Round 8
// 12.365 us; speedup vs baseline: 1.0026x; 1.0026x over previous
//
#include <hip/hip_runtime.h>

// PairwiseRankingLoss: B=128 rows, L=1024.
// loss = sum_{b, pos i, neg j} relu(1 - s[b,i] + s[b,j]) / max(num_pairs, 1)
//
// K1: grid = B*SPLIT (SPLIT=16) blocks, 8 blocks/CU (full 32 waves/CU).
//     Each block ballot-compacts its row into dense pos[] / neg[] LDS arrays
//     (labels are {0,1} so neg-mask = ~pos-mask, nn = L - np), then computes
//     the hinge over (all pos) x (its 1/16 slice of compacted negs).
//     Partial sums to distinct ws slots; s==0 block writes exact np*(L-np).
// K2: one 64-thread wave reduces the 2048 partials and writes the loss.

#define PRL_B 128
#define PRL_L 1024
#define SPLIT 16
#define NBLK  (PRL_B * SPLIT)   // 2048 blocks

// Hot loop specialized on K = pos values per thread (block-uniform runtime).
template<int K>
__device__ __forceinline__ float hotloop(const float4* __restrict__ d4,
                                         int c0, int c1, float4 pv) {
    float acc[K];
#pragma unroll
    for (int k = 0; k < K; ++k) acc[k] = 0.f;
#pragma unroll 2
    for (int c = c0; c < c1; ++c) {
        const float4 d = d4[c];   // wave-uniform LDS broadcast
#pragma unroll
        for (int k = 0; k < K; ++k) {
            const float pk = (k == 0) ? pv.x : (k == 1) ? pv.y : (k == 2) ? pv.z : pv.w;
            acc[k] += (fmaxf(d.x - pk, 0.f) + fmaxf(d.y - pk, 0.f))
                    + (fmaxf(d.z - pk, 0.f) + fmaxf(d.w - pk, 0.f));
        }
    }
    float r = 0.f;
#pragma unroll
    for (int k = 0; k < K; ++k) r += acc[k];
    return r;
}

__global__ __launch_bounds__(256) void prl_partial(
    const float* __restrict__ y_pred,
    const int*   __restrict__ y_true,
    float* __restrict__ bsum,    // [NBLK]
    int*   __restrict__ bpairs)  // [NBLK]
{
    __shared__ float4 s_pos4[PRL_L / 4];   // compacted pos scores (+3e38 pad)
    __shared__ float4 s_neg4[PRL_L / 4];   // compacted 1+neg scores (-3e38 pad)
    __shared__ int    s_cntP[4];
    __shared__ float  s_wsum[4];
    float* s_pos = (float*)s_pos4;
    float* s_neg = (float*)s_neg4;

    const int blk  = blockIdx.x;
    const int b    = blk >> 4;            // / SPLIT
    const int s    = blk & (SPLIT - 1);
    const int t    = threadIdx.x;
    const int lane = t & 63;
    const int w    = t >> 6;

    // Vectorized staging: one float4 + one int4 per thread covers the row.
    // Element e = 256*w + 4*lane + r.
    const float4 sc = ((const float4*)(y_pred + (size_t)b * PRL_L))[t];
    const int4   lv = ((const int4*)  (y_true + (size_t)b * PRL_L))[t];
    const float sv[4] = {sc.x, sc.y, sc.z, sc.w};
    const int   lb[4] = {lv.x, lv.y, lv.z, lv.w};

    // Pass 1: per-wave pos masks via ballot; labels in {0,1} => neg = ~pos.
    unsigned long long mP[4];
    int cP = 0;
#pragma unroll
    for (int r = 0; r < 4; ++r) {
        mP[r] = __ballot(lb[r] == 1);
        cP += (int)__popcll(mP[r]);
    }
    if (lane == 0) s_cntP[w] = cP;

    // Sentinel-init (pad regions survive; valid regions overwritten below).
    s_pos4[t] = make_float4( 3.0e38f,  3.0e38f,  3.0e38f,  3.0e38f);
    s_neg4[t] = make_float4(-3.0e38f, -3.0e38f, -3.0e38f, -3.0e38f);
    __syncthreads();

    // Wave offsets + row totals (np; nn = L - np).
    int offP = 0, np = 0;
#pragma unroll
    for (int ww = 0; ww < 4; ++ww) {
        const int p_ = s_cntP[ww];
        np += p_;
        if (ww < w) offP += p_;
    }
    const int nn   = PRL_L - np;
    const int offN = 256 * w - offP;

    // Pass 2: scatter compacted values (order irrelevant).
    const unsigned long long lt = (1ULL << lane) - 1ULL;
    int bP = offP, bN = offN;
#pragma unroll
    for (int r = 0; r < 4; ++r) {
        const unsigned long long mp = mP[r], mn = ~mp;
        if (lb[r] == 1) s_pos[bP + (int)__popcll(mp & lt)] = sv[r];
        else            s_neg[bN + (int)__popcll(mn & lt)] = 1.0f + sv[r];
        bP += (int)__popcll(mp);
        bN += 64 - (int)__popcll(mp);
    }
    __syncthreads();

    // This thread's pos values (sentinel-padded reads are safe).
    const float4 pv = make_float4(s_pos[t], s_pos[t + 256],
                                  s_pos[t + 512], s_pos[t + 768]);
    const int KP  = (np + 255) >> 8;              // 0..4, block-uniform
    const int NN4 = (nn + 3) >> 2;                // float4 groups of negs
    const int G   = (NN4 + SPLIT - 1) / SPLIT;    // groups per slice
    const int c0  = min(s * G, NN4);
    const int c1  = min(c0 + G, NN4);

    float local;
    switch (KP) {
        case 0:  local = 0.f; break;
        case 1:  local = hotloop<1>(s_neg4, c0, c1, pv); break;
        case 2:  local = hotloop<2>(s_neg4, c0, c1, pv); break;
        case 3:  local = hotloop<3>(s_neg4, c0, c1, pv); break;
        default: local = hotloop<4>(s_neg4, c0, c1, pv); break;
    }

    // Block reduction (sum only; pair count is uniform, no reduce needed).
#pragma unroll
    for (int off = 32; off >= 1; off >>= 1)
        local += __shfl_down(local, off, 64);
    if (lane == 0) s_wsum[w] = local;
    __syncthreads();

    if (t == 0) {
        bsum[blk]   = (s_wsum[0] + s_wsum[1]) + (s_wsum[2] + s_wsum[3]);
        bpairs[blk] = (s == 0) ? np * nn : 0;   // exact pair count, once/row
    }
}

// Single-wave finalize: 64 threads read all 2048 partials (16 KB, L2-hot).
__global__ __launch_bounds__(64) void prl_finalize(
    const float* __restrict__ bsum,
    const int*   __restrict__ bpairs,
    float* __restrict__ out)
{
    const int t = threadIdx.x;
    const float4* s4 = (const float4*)bsum;
    const int4*   p4 = (const int4*)bpairs;

    float fs = 0.f; int ps = 0;
#pragma unroll
    for (int k = 0; k < 8; ++k) {           // 8 x 64 float4 = 2048 partials
        const float4 a = s4[t + 64 * k];
        const int4  ia = p4[t + 64 * k];
        fs += (a.x + a.y) + (a.z + a.w);
        ps += (ia.x + ia.y) + (ia.z + ia.w);
    }
#pragma unroll
    for (int off = 32; off >= 1; off >>= 1) {
        fs += __shfl_down(fs, off, 64);
        ps += __shfl_down(ps, off, 64);
    }
    if (t == 0)
        out[0] = (ps > 0) ? (fs / fmaxf((float)ps, 1.0f)) : fs;
}

extern "C" void kernel_launch(void* const* d_in, const int* in_sizes, int n_in,
                              void* d_out, int out_size, void* d_ws, size_t ws_size,
                              hipStream_t stream) {
    const float* y_pred = (const float*)d_in[0];
    const int*   y_true = (const int*)d_in[1];
    float* out = (float*)d_out;

    // ws layout: float bsum[NBLK]; int bpairs[NBLK]
    float* bsum   = (float*)d_ws;
    int*   bpairs = (int*)((char*)d_ws + NBLK * sizeof(float));

    prl_partial<<<NBLK, 256, 0, stream>>>(y_pred, y_true, bsum, bpairs);
    prl_finalize<<<1, 64, 0, stream>>>(bsum, bpairs, out);
}